// Round 11
// baseline (306.376 us; speedup 1.0000x reference)
//
#include <hip/hip_runtime.h>
#include <hip/hip_bf16.h>
#include <math.h>

#define N_NODES 50000
#define N_EDGES 600000
#define D_IN    44

// ---------------- CSR build ----------------

__global__ void k_zero(int* p, int n) {
    int i = blockIdx.x * blockDim.x + threadIdx.x;
    if (i < n) p[i] = 0;
}

__global__ void k_count(const int* __restrict__ dst, int* degc, int e) {
    int i = blockIdx.x * blockDim.x + threadIdx.x;
    if (i < e) atomicAdd(&degc[dst[i]], 1);
}

__global__ void k_blocksum(const int* __restrict__ degc, int* __restrict__ bsum, int n) {
    int i = blockIdx.x * 256 + threadIdx.x;
    int v = (i < n) ? degc[i] : 0;
    #pragma unroll
    for (int off = 32; off > 0; off >>= 1) v += __shfl_down(v, off, 64);
    __shared__ int ws[4];
    if ((threadIdx.x & 63) == 0) ws[threadIdx.x >> 6] = v;
    __syncthreads();
    if (threadIdx.x == 0) bsum[blockIdx.x] = ws[0] + ws[1] + ws[2] + ws[3];
}

__global__ void k_scanbsum(int* bsum, int nb) {
    __shared__ int s[256];
    int t = threadIdx.x;
    int v = (t < nb) ? bsum[t] : 0;
    s[t] = v;
    __syncthreads();
    #pragma unroll
    for (int off = 1; off < 256; off <<= 1) {
        int u = (t >= off) ? s[t - off] : 0;
        __syncthreads();
        s[t] += u;
        __syncthreads();
    }
    if (t < nb) bsum[t] = (t == 0) ? 0 : s[t - 1];
}

__global__ void k_rowptr(const int* __restrict__ degc, const int* __restrict__ bsum,
                         int* __restrict__ row_ptr, int* __restrict__ cursor,
                         float* __restrict__ dinv, int n) {
    __shared__ int s[256];
    int i = blockIdx.x * 256 + threadIdx.x;
    int t = threadIdx.x;
    int d = (i < n) ? degc[i] : 0;
    s[t] = d;
    __syncthreads();
    #pragma unroll
    for (int off = 1; off < 256; off <<= 1) {
        int u = (t >= off) ? s[t - off] : 0;
        __syncthreads();
        s[t] += u;
        __syncthreads();
    }
    int ex = s[t] - d + bsum[blockIdx.x];
    if (i < n) {
        row_ptr[i] = ex;
        cursor[i]  = ex;
        dinv[i]    = rsqrtf(1.0f + (float)d);
        if (i == n - 1) row_ptr[n] = ex + d;
    }
}

__global__ void k_fill(const int* __restrict__ src, const int* __restrict__ dst,
                       const float* __restrict__ dinv, int* cursor,
                       int2* __restrict__ csr_ew, int e) {
    int i = blockIdx.x * blockDim.x + threadIdx.x;
    if (i < e) {
        int s = src[i], d = dst[i];
        int p = atomicAdd(&cursor[d], 1);
        csr_ew[p] = make_int2(s, __float_as_int(dinv[s] * dinv[d]));
    }
}

// predicated 4-deep gather of one float4 chunk of one node's aggregation
__device__ __forceinline__ float4 agg_row(const float4* __restrict__ T4, int W4, int j,
                                          float sw, float4 self,
                                          const int* __restrict__ row_ptr,
                                          const int2* __restrict__ csr_ew, int g) {
    float4 acc = make_float4(sw * self.x, sw * self.y, sw * self.z, sw * self.w);
    int lo = row_ptr[g], hi = row_ptr[g + 1];
    for (int k = lo; k < hi; k += 4) {
        int2 e0 = csr_ew[min(k + 0, hi - 1)];
        int2 e1 = csr_ew[min(k + 1, hi - 1)];
        int2 e2 = csr_ew[min(k + 2, hi - 1)];
        int2 e3 = csr_ew[min(k + 3, hi - 1)];
        float w0 = __int_as_float(e0.y);
        float w1 = (k + 1 < hi) ? __int_as_float(e1.y) : 0.0f;
        float w2 = (k + 2 < hi) ? __int_as_float(e2.y) : 0.0f;
        float w3 = (k + 3 < hi) ? __int_as_float(e3.y) : 0.0f;
        float4 t0 = T4[(size_t)e0.x * W4 + j];
        float4 t1 = T4[(size_t)e1.x * W4 + j];
        float4 t2 = T4[(size_t)e2.x * W4 + j];
        float4 t3 = T4[(size_t)e3.x * W4 + j];
        acc.x += w0 * t0.x; acc.y += w0 * t0.y; acc.z += w0 * t0.z; acc.w += w0 * t0.w;
        acc.x += w1 * t1.x; acc.y += w1 * t1.y; acc.z += w1 * t1.z; acc.w += w1 * t1.w;
        acc.x += w2 * t2.x; acc.y += w2 * t2.y; acc.z += w2 * t2.z; acc.w += w2 * t2.w;
        acc.x += w3 * t3.x; acc.y += w3 * t3.y; acc.z += w3 * t3.z; acc.w += w3 * t3.w;
    }
    return acc;
}

// ---------------- fused layer 1: agg(x,44) -> gemm1(44->128,+b1,relu) -> gemm2(128->64) ----
// 16 nodes / 256-thread block.

__global__ void __launch_bounds__(256) k_fused1(
        const float* __restrict__ x, const float* __restrict__ dinv,
        const int* __restrict__ row_ptr, const int2* __restrict__ csr_ew,
        const float* __restrict__ W1, const float* __restrict__ b1,
        const float* __restrict__ W2, float* __restrict__ outA, int n) {
    __shared__ float Xs[16 * 44];          // agg'd x rows
    __shared__ float Hs[16 * 132];         // h1 rows (128 + 4 pad)
    const int m = threadIdx.x / 16;
    const int j = threadIdx.x % 16;
    const int g = blockIdx.x * 16 + m;

    // phase A: gather-aggregate x (W4 = 11)
    if (g < n && j < 11) {
        float di = dinv[g];
        float4 self = ((const float4*)x)[(size_t)g * 11 + j];
        float4 a = agg_row((const float4*)x, 11, j, di * di, self, row_ptr, csr_ew, g);
        *(float4*)&Xs[m * 44 + 4 * j] = a;
    }
    __syncthreads();

    // phase B: h1 = relu(Xs @ W1 + b1) -> Hs. cols c0 = (j)*8
    {
        const int c0 = j * 8;
        float4 a0 = *(const float4*)&b1[c0];
        float4 a1 = *(const float4*)&b1[c0 + 4];
        #pragma unroll
        for (int k4 = 0; k4 < 11; ++k4) {
            float4 xv = *(const float4*)&Xs[m * 44 + 4 * k4];
            #define F1_STEP(xs, kk) { \
                float4 w0 = *(const float4*)&W1[(kk) * 128 + c0];     \
                float4 w1 = *(const float4*)&W1[(kk) * 128 + c0 + 4]; \
                a0.x += (xs) * w0.x; a0.y += (xs) * w0.y; a0.z += (xs) * w0.z; a0.w += (xs) * w0.w; \
                a1.x += (xs) * w1.x; a1.y += (xs) * w1.y; a1.z += (xs) * w1.z; a1.w += (xs) * w1.w; }
            F1_STEP(xv.x, 4 * k4 + 0)
            F1_STEP(xv.y, 4 * k4 + 1)
            F1_STEP(xv.z, 4 * k4 + 2)
            F1_STEP(xv.w, 4 * k4 + 3)
            #undef F1_STEP
        }
        a0.x = fmaxf(a0.x, 0.0f); a0.y = fmaxf(a0.y, 0.0f);
        a0.z = fmaxf(a0.z, 0.0f); a0.w = fmaxf(a0.w, 0.0f);
        a1.x = fmaxf(a1.x, 0.0f); a1.y = fmaxf(a1.y, 0.0f);
        a1.z = fmaxf(a1.z, 0.0f); a1.w = fmaxf(a1.w, 0.0f);
        *(float4*)&Hs[m * 132 + c0]     = a0;
        *(float4*)&Hs[m * 132 + c0 + 4] = a1;
    }
    __syncthreads();

    // phase C: t2 = Hs @ W2 (128->64) -> outA. cols c2 = j*4
    {
        const int c2 = j * 4;
        float4 a = make_float4(0.f, 0.f, 0.f, 0.f);
        #pragma unroll 8
        for (int k4 = 0; k4 < 32; ++k4) {
            float4 hv = *(const float4*)&Hs[m * 132 + 4 * k4];
            #define F2_STEP(hs, kk) { \
                float4 wv = *(const float4*)&W2[(kk) * 64 + c2]; \
                a.x += (hs) * wv.x; a.y += (hs) * wv.y; a.z += (hs) * wv.z; a.w += (hs) * wv.w; }
            F2_STEP(hv.x, 4 * k4 + 0)
            F2_STEP(hv.y, 4 * k4 + 1)
            F2_STEP(hv.z, 4 * k4 + 2)
            F2_STEP(hv.w, 4 * k4 + 3)
            #undef F2_STEP
        }
        if (g < n) *(float4*)&outA[(size_t)g * 64 + c2] = a;
    }
}

// ---------------- fused layer 2: agg(t2,64,+b2,relu) -> gemm3(64->32) ----------------
// 16 nodes / block.

__global__ void __launch_bounds__(256) k_fused2(
        const float* __restrict__ T, const float* __restrict__ dinv,
        const int* __restrict__ row_ptr, const int2* __restrict__ csr_ew,
        const float* __restrict__ b2, const float* __restrict__ W3,
        float* __restrict__ outB, int n) {
    __shared__ float Xs[16 * 68];          // agg'd rows (64 + 4 pad)
    const int m = threadIdx.x / 16;
    const int j = threadIdx.x % 16;
    const int g = blockIdx.x * 16 + m;

    if (g < n) {
        float di = dinv[g];
        float4 self = ((const float4*)T)[(size_t)g * 16 + j];
        float4 a = agg_row((const float4*)T, 16, j, di * di, self, row_ptr, csr_ew, g);
        float4 bv = ((const float4*)b2)[j];
        a.x = fmaxf(a.x + bv.x, 0.0f);
        a.y = fmaxf(a.y + bv.y, 0.0f);
        a.z = fmaxf(a.z + bv.z, 0.0f);
        a.w = fmaxf(a.w + bv.w, 0.0f);
        *(float4*)&Xs[m * 68 + 4 * j] = a;
    }
    __syncthreads();

    // t3 = Xs @ W3 (64->32): cols c = j*2
    {
        const int c = j * 2;
        float ax = 0.0f, ay = 0.0f;
        #pragma unroll 4
        for (int k4 = 0; k4 < 16; ++k4) {
            float4 hv = *(const float4*)&Xs[m * 68 + 4 * k4];
            #define F3_STEP(hs, kk) { \
                float2 wv = *(const float2*)&W3[(kk) * 32 + c]; \
                ax += (hs) * wv.x; ay += (hs) * wv.y; }
            F3_STEP(hv.x, 4 * k4 + 0)
            F3_STEP(hv.y, 4 * k4 + 1)
            F3_STEP(hv.z, 4 * k4 + 2)
            F3_STEP(hv.w, 4 * k4 + 3)
            #undef F3_STEP
        }
        if (g < n) *(float2*)&outB[(size_t)g * 32 + c] = make_float2(ax, ay);
    }
}

// ---------------- fused layer 3 + head: agg(t3,32,+b3,relu) -> MLP -> sigmoid ----------
// 32 nodes / block; 8 lanes per node.

__global__ void __launch_bounds__(256) k_fused3(
        const float* __restrict__ T, const float* __restrict__ dinv,
        const int* __restrict__ row_ptr, const int2* __restrict__ csr_ew,
        const float* __restrict__ b3,
        const float* __restrict__ Wf1, const float* __restrict__ bf1,
        const float* __restrict__ Wf2, const float* __restrict__ bf2,
        float* __restrict__ out, int n) {
    __shared__ float Xs[32 * 36];          // agg'd rows (32 + 4 pad)
    __shared__ float W1s[32 * 16];
    __shared__ float b1s[16];
    __shared__ float W2s[16];
    __shared__ float b2s;
    const int t = threadIdx.x;
    for (int i = t; i < 32 * 16; i += 256) W1s[i] = Wf1[i];
    if (t < 16) { b1s[t] = bf1[t]; W2s[t] = Wf2[t]; }
    if (t == 0) b2s = bf2[0];

    const int m = t / 8;
    const int j = t % 8;
    const int g = blockIdx.x * 32 + m;

    if (g < n) {
        float di = dinv[g];
        float4 self = ((const float4*)T)[(size_t)g * 8 + j];
        float4 a = agg_row((const float4*)T, 8, j, di * di, self, row_ptr, csr_ew, g);
        float4 bv = ((const float4*)b3)[j];
        a.x = fmaxf(a.x + bv.x, 0.0f);
        a.y = fmaxf(a.y + bv.y, 0.0f);
        a.z = fmaxf(a.z + bv.z, 0.0f);
        a.w = fmaxf(a.w + bv.w, 0.0f);
        *(float4*)&Xs[m * 36 + 4 * j] = a;
    }
    __syncthreads();

    // MLP: lane j computes hidden 2j, 2j+1; shuffle-reduce 8 lanes
    {
        const int c = j * 2;
        float h0 = b1s[c], h1 = b1s[c + 1];
        #pragma unroll
        for (int k = 0; k < 32; ++k) {
            float xs = Xs[m * 36 + k];
            h0 += xs * W1s[k * 16 + c];
            h1 += xs * W1s[k * 16 + c + 1];
        }
        float partial = fmaxf(h0, 0.0f) * W2s[c] + fmaxf(h1, 0.0f) * W2s[c + 1];
        partial += __shfl_down(partial, 4);
        partial += __shfl_down(partial, 2);
        partial += __shfl_down(partial, 1);
        if (j == 0 && g < n) out[g] = 1.0f / (1.0f + expf(-(partial + b2s)));
    }
}

// ---------------- launch ----------------

extern "C" void kernel_launch(void* const* d_in, const int* in_sizes, int n_in,
                              void* d_out, int out_size, void* d_ws, size_t ws_size,
                              hipStream_t stream) {
    const float* x   = (const float*)d_in[0];
    const int*   ei  = (const int*)d_in[1];
    const float* W1  = (const float*)d_in[2];
    const float* b1  = (const float*)d_in[3];
    const float* W2  = (const float*)d_in[4];
    const float* b2  = (const float*)d_in[5];
    const float* W3  = (const float*)d_in[6];
    const float* b3  = (const float*)d_in[7];
    const float* Wf1 = (const float*)d_in[8];
    const float* bf1 = (const float*)d_in[9];
    const float* Wf2 = (const float*)d_in[10];
    const float* bf2 = (const float*)d_in[11];
    float* out = (float*)d_out;

    const int N = N_NODES, E = N_EDGES;
    const int* src = ei;
    const int* dst = ei + E;

    char* w = (char*)d_ws;
    float* dinv    = (float*)w;                     w += (size_t)N * 4;
    int*   degc    = (int*)w;                       w += (size_t)N * 4;
    int*   row_ptr = (int*)w;                       w += (size_t)(N + 4) * 4;
    int*   cursor  = (int*)w;                       w += (size_t)N * 4;
    int*   bsum    = (int*)w;                       w += (size_t)256 * 4;
    int2*  csr_ew  = (int2*)w;                      w += (size_t)E * 8;
    float* bufA    = (float*)w;                     w += (size_t)N * 64 * 4;   // t2 (64-wide)
    float* bufB    = (float*)w;                                                // t3 (32-wide)

    const int B  = 256;
    const int NB = (N + B - 1) / B;        // 196

    // ---- CSR build ----
    k_zero     <<<NB, B, 0, stream>>>(degc, N);
    k_count    <<<(E + B - 1) / B, B, 0, stream>>>(dst, degc, E);
    k_blocksum <<<NB, B, 0, stream>>>(degc, bsum, N);
    k_scanbsum <<<1, B, 0, stream>>>(bsum, NB);
    k_rowptr   <<<NB, B, 0, stream>>>(degc, bsum, row_ptr, cursor, dinv, N);
    k_fill     <<<(E + B - 1) / B, B, 0, stream>>>(src, dst, dinv, cursor, csr_ew, E);

    // ---- fused layers ----
    k_fused1<<<(N + 15) / 16, B, 0, stream>>>(x, dinv, row_ptr, csr_ew, W1, b1, W2, bufA, N);
    k_fused2<<<(N + 15) / 16, B, 0, stream>>>(bufA, dinv, row_ptr, csr_ew, b2, W3, bufB, N);
    k_fused3<<<(N + 31) / 32, B, 0, stream>>>(bufB, dinv, row_ptr, csr_ew, b3,
                                              Wf1, bf1, Wf2, bf2, out, N);
}

// Round 12
// 283.046 us; speedup vs baseline: 1.0824x; 1.0824x over previous
//
#include <hip/hip_runtime.h>
#include <hip/hip_bf16.h>
#include <math.h>

#define N_NODES 50000
#define N_EDGES 600000
#define D_IN    44

// ---------------- bf16 helpers (bit ops, RNE pack) ----------------

__device__ __forceinline__ unsigned pack_bf2(float a, float b) {
    unsigned ua = __float_as_uint(a);
    ua = (ua + 0x7fffu + ((ua >> 16) & 1u)) >> 16;
    unsigned ub = __float_as_uint(b);
    ub = (ub + 0x7fffu + ((ub >> 16) & 1u)) & 0xffff0000u;
    return ua | ub;
}

// ---------------- CSR build ----------------

__global__ void k_zero(int* p, int n) {
    int i = blockIdx.x * blockDim.x + threadIdx.x;
    if (i < n) p[i] = 0;
}

__global__ void k_count(const int* __restrict__ dst, int* degc, int e) {
    int i = blockIdx.x * blockDim.x + threadIdx.x;
    if (i < e) atomicAdd(&degc[dst[i]], 1);
}

__global__ void k_blocksum(const int* __restrict__ degc, int* __restrict__ bsum, int n) {
    int i = blockIdx.x * 256 + threadIdx.x;
    int v = (i < n) ? degc[i] : 0;
    #pragma unroll
    for (int off = 32; off > 0; off >>= 1) v += __shfl_down(v, off, 64);
    __shared__ int ws[4];
    if ((threadIdx.x & 63) == 0) ws[threadIdx.x >> 6] = v;
    __syncthreads();
    if (threadIdx.x == 0) bsum[blockIdx.x] = ws[0] + ws[1] + ws[2] + ws[3];
}

__global__ void k_scanbsum(int* bsum, int nb) {
    __shared__ int s[256];
    int t = threadIdx.x;
    int v = (t < nb) ? bsum[t] : 0;
    s[t] = v;
    __syncthreads();
    #pragma unroll
    for (int off = 1; off < 256; off <<= 1) {
        int u = (t >= off) ? s[t - off] : 0;
        __syncthreads();
        s[t] += u;
        __syncthreads();
    }
    if (t < nb) bsum[t] = (t == 0) ? 0 : s[t - 1];
}

__global__ void k_rowptr(const int* __restrict__ degc, const int* __restrict__ bsum,
                         int* __restrict__ row_ptr, int* __restrict__ cursor,
                         float* __restrict__ dinv, int n) {
    __shared__ int s[256];
    int i = blockIdx.x * 256 + threadIdx.x;
    int t = threadIdx.x;
    int d = (i < n) ? degc[i] : 0;
    s[t] = d;
    __syncthreads();
    #pragma unroll
    for (int off = 1; off < 256; off <<= 1) {
        int u = (t >= off) ? s[t - off] : 0;
        __syncthreads();
        s[t] += u;
        __syncthreads();
    }
    int ex = s[t] - d + bsum[blockIdx.x];
    if (i < n) {
        row_ptr[i] = ex;
        cursor[i]  = ex;
        dinv[i]    = rsqrtf(1.0f + (float)d);
        if (i == n - 1) row_ptr[n] = ex + d;
    }
}

__global__ void k_fill(const int* __restrict__ src, const int* __restrict__ dst,
                       const float* __restrict__ dinv, int* cursor,
                       int2* __restrict__ csr_ew, int e) {
    int i = blockIdx.x * blockDim.x + threadIdx.x;
    if (i < e) {
        int s = src[i], d = dst[i];
        int p = atomicAdd(&cursor[d], 1);
        csr_ew[p] = make_int2(s, __float_as_int(dinv[s] * dinv[d]));
    }
}

// ---------------- pack x (fp32) -> xh (bf16) ----------------

__global__ void k_packx(const float* __restrict__ x, unsigned* __restrict__ xh, int npairs) {
    int i = blockIdx.x * blockDim.x + threadIdx.x;
    if (i < npairs) {
        float2 v = ((const float2*)x)[i];
        xh[i] = pack_bf2(v.x, v.y);
    }
}

// ---------------- CSR gather-aggregate from bf16 source, fp32 out ----------------
// Lane idx -> (node g, 4-feature chunk j). Source row = W4 uint2 chunks (4 bf16).
// Predicated 8-deep gather: 8 loads in flight, no serial tail.

template<int W4, bool BIAS_RELU>
__global__ void k_agg(const unsigned* __restrict__ T, const float* __restrict__ dinv,
                      const int* __restrict__ row_ptr, const int2* __restrict__ csr_ew,
                      const float* __restrict__ b, float* __restrict__ O, int n) {
    int idx = blockIdx.x * 256 + threadIdx.x;
    if (idx >= n * W4) return;
    int g = idx / W4;
    int j = idx - g * W4;

    const uint2* T2 = (const uint2*)T;
    float di = dinv[g];
    float sw = di * di;
    uint2 sv = T2[(size_t)g * W4 + j];
    float4 acc;
    acc.x = sw * __uint_as_float(sv.x << 16);
    acc.y = sw * __uint_as_float(sv.x & 0xffff0000u);
    acc.z = sw * __uint_as_float(sv.y << 16);
    acc.w = sw * __uint_as_float(sv.y & 0xffff0000u);

    int lo = row_ptr[g], hi = row_ptr[g + 1];
    for (int k = lo; k < hi; k += 8) {
#define AGG_SLOT(i, ev, tv, wv) \
        int2 ev = csr_ew[min(k + (i), hi - 1)]; \
        float wv = (k + (i) < hi) ? __int_as_float(ev.y) : 0.0f; \
        uint2 tv = T2[(size_t)ev.x * W4 + j];
        AGG_SLOT(0, e0, t0, w0)
        AGG_SLOT(1, e1, t1, w1)
        AGG_SLOT(2, e2, t2, w2)
        AGG_SLOT(3, e3, t3, w3)
        AGG_SLOT(4, e4, t4, w4)
        AGG_SLOT(5, e5, t5, w5)
        AGG_SLOT(6, e6, t6, w6)
        AGG_SLOT(7, e7, t7, w7)
#undef AGG_SLOT
#define AGG_ACC(tv, wv) \
        acc.x += wv * __uint_as_float(tv.x << 16); \
        acc.y += wv * __uint_as_float(tv.x & 0xffff0000u); \
        acc.z += wv * __uint_as_float(tv.y << 16); \
        acc.w += wv * __uint_as_float(tv.y & 0xffff0000u);
        AGG_ACC(t0, w0) AGG_ACC(t1, w1) AGG_ACC(t2, w2) AGG_ACC(t3, w3)
        AGG_ACC(t4, w4) AGG_ACC(t5, w5) AGG_ACC(t6, w6) AGG_ACC(t7, w7)
#undef AGG_ACC
    }
    if (BIAS_RELU) {
        float4 bv = ((const float4*)b)[j];
        acc.x = fmaxf(acc.x + bv.x, 0.0f);
        acc.y = fmaxf(acc.y + bv.y, 0.0f);
        acc.z = fmaxf(acc.z + bv.z, 0.0f);
        acc.w = fmaxf(acc.w + bv.w, 0.0f);
    }
    ((float4*)O)[(size_t)g * W4 + j] = acc;
}

// ---------------- register-blocked GEMM, uniform (scalar) W loads ----------------
// Optional bf16-packed output (for gather-source buffers).

template<int DI, int DO, int CT, bool BIAS_RELU, bool OUT_BF16>
__global__ void k_gemm(const float* __restrict__ X, const float* __restrict__ W,
                       const float* __restrict__ b, void* __restrict__ H, int n) {
    const int ct0 = blockIdx.y * CT;
    int node = blockIdx.x * blockDim.x + threadIdx.x;
    if (node >= n) return;

    float acc[CT];
    #pragma unroll
    for (int c = 0; c < CT; ++c) acc[c] = BIAS_RELU ? b[ct0 + c] : 0.0f;

    const float4* xr = (const float4*)(X + (size_t)node * DI);
    const float*  Wb = W + ct0;
    #pragma unroll
    for (int k0 = 0; k0 < DI / 4; ++k0) {
        float4 xv = xr[k0];
        #pragma unroll
        for (int c = 0; c < CT; ++c) acc[c] += xv.x * Wb[(k0 * 4 + 0) * DO + c];
        #pragma unroll
        for (int c = 0; c < CT; ++c) acc[c] += xv.y * Wb[(k0 * 4 + 1) * DO + c];
        #pragma unroll
        for (int c = 0; c < CT; ++c) acc[c] += xv.z * Wb[(k0 * 4 + 2) * DO + c];
        #pragma unroll
        for (int c = 0; c < CT; ++c) acc[c] += xv.w * Wb[(k0 * 4 + 3) * DO + c];
    }

    #pragma unroll
    for (int c4 = 0; c4 < CT / 4; ++c4) {
        float4 v;
        v.x = acc[c4 * 4 + 0]; v.y = acc[c4 * 4 + 1];
        v.z = acc[c4 * 4 + 2]; v.w = acc[c4 * 4 + 3];
        if (BIAS_RELU) {
            v.x = fmaxf(v.x, 0.0f); v.y = fmaxf(v.y, 0.0f);
            v.z = fmaxf(v.z, 0.0f); v.w = fmaxf(v.w, 0.0f);
        }
        if (OUT_BF16) {
            uint2 p;
            p.x = pack_bf2(v.x, v.y);
            p.y = pack_bf2(v.z, v.w);
            ((uint2*)((unsigned short*)H + (size_t)node * DO + ct0))[c4] = p;
        } else {
            ((float4*)((float*)H + (size_t)node * DO + ct0))[c4] = v;
        }
    }
}

// ---------------- MLP head ----------------

__global__ void __launch_bounds__(64) k_mlp(
        const float* __restrict__ O3,
        const float* __restrict__ Wf1, const float* __restrict__ bf1,
        const float* __restrict__ Wf2, const float* __restrict__ bf2,
        float* __restrict__ out, int n) {
    __shared__ float W1s[32 * 16];
    __shared__ float b1s[16];
    __shared__ float W2s[16];
    __shared__ float b2s;
    int t = threadIdx.x;
    for (int i = t; i < 32 * 16; i += 64) W1s[i] = Wf1[i];
    if (t < 16) { b1s[t] = bf1[t]; W2s[t] = Wf2[t]; }
    if (t == 0) b2s = bf2[0];
    __syncthreads();

    int node = blockIdx.x * 64 + t;
    if (node >= n) return;

    const float4* xr = (const float4*)(O3 + (size_t)node * 32);
    float4 h0 = *(const float4*)&b1s[0];
    float4 h1 = *(const float4*)&b1s[4];
    float4 h2 = *(const float4*)&b1s[8];
    float4 h3 = *(const float4*)&b1s[12];

#define MLP_STEP(xs, krow) { \
        float4 wa = *(const float4*)&W1s[(krow) * 16 + 0];  \
        float4 wb = *(const float4*)&W1s[(krow) * 16 + 4];  \
        float4 wc = *(const float4*)&W1s[(krow) * 16 + 8];  \
        float4 wd = *(const float4*)&W1s[(krow) * 16 + 12]; \
        h0.x += (xs) * wa.x; h0.y += (xs) * wa.y; h0.z += (xs) * wa.z; h0.w += (xs) * wa.w; \
        h1.x += (xs) * wb.x; h1.y += (xs) * wb.y; h1.z += (xs) * wb.z; h1.w += (xs) * wb.w; \
        h2.x += (xs) * wc.x; h2.y += (xs) * wc.y; h2.z += (xs) * wc.z; h2.w += (xs) * wc.w; \
        h3.x += (xs) * wd.x; h3.y += (xs) * wd.y; h3.z += (xs) * wd.z; h3.w += (xs) * wd.w; }

    #pragma unroll
    for (int k4 = 0; k4 < 8; ++k4) {
        float4 xv = xr[k4];
        MLP_STEP(xv.x, k4 * 4 + 0)
        MLP_STEP(xv.y, k4 * 4 + 1)
        MLP_STEP(xv.z, k4 * 4 + 2)
        MLP_STEP(xv.w, k4 * 4 + 3)
    }
#undef MLP_STEP

    float4 va = *(const float4*)&W2s[0];
    float4 vb = *(const float4*)&W2s[4];
    float4 vc = *(const float4*)&W2s[8];
    float4 vd = *(const float4*)&W2s[12];
    float acc = b2s
        + fmaxf(h0.x, 0.0f) * va.x + fmaxf(h0.y, 0.0f) * va.y
        + fmaxf(h0.z, 0.0f) * va.z + fmaxf(h0.w, 0.0f) * va.w
        + fmaxf(h1.x, 0.0f) * vb.x + fmaxf(h1.y, 0.0f) * vb.y
        + fmaxf(h1.z, 0.0f) * vb.z + fmaxf(h1.w, 0.0f) * vb.w
        + fmaxf(h2.x, 0.0f) * vc.x + fmaxf(h2.y, 0.0f) * vc.y
        + fmaxf(h2.z, 0.0f) * vc.z + fmaxf(h2.w, 0.0f) * vc.w
        + fmaxf(h3.x, 0.0f) * vd.x + fmaxf(h3.y, 0.0f) * vd.y
        + fmaxf(h3.z, 0.0f) * vd.z + fmaxf(h3.w, 0.0f) * vd.w;
    out[node] = 1.0f / (1.0f + expf(-acc));
}

// ---------------- launch ----------------

extern "C" void kernel_launch(void* const* d_in, const int* in_sizes, int n_in,
                              void* d_out, int out_size, void* d_ws, size_t ws_size,
                              hipStream_t stream) {
    const float* x   = (const float*)d_in[0];
    const int*   ei  = (const int*)d_in[1];
    const float* W1  = (const float*)d_in[2];
    const float* b1  = (const float*)d_in[3];
    const float* W2  = (const float*)d_in[4];
    const float* b2  = (const float*)d_in[5];
    const float* W3  = (const float*)d_in[6];
    const float* b3  = (const float*)d_in[7];
    const float* Wf1 = (const float*)d_in[8];
    const float* bf1 = (const float*)d_in[9];
    const float* Wf2 = (const float*)d_in[10];
    const float* bf2 = (const float*)d_in[11];
    float* out = (float*)d_out;

    const int N = N_NODES, E = N_EDGES;
    const int* src = ei;
    const int* dst = ei + E;

    char* w = (char*)d_ws;
    float*    dinv    = (float*)w;     w += (size_t)N * 4;
    int*      degc    = (int*)w;       w += (size_t)N * 4;
    int*      row_ptr = (int*)w;       w += (size_t)(N + 4) * 4;
    int*      cursor  = (int*)w;       w += (size_t)N * 4;
    int*      bsum    = (int*)w;       w += (size_t)256 * 4;
    int2*     csr_ew  = (int2*)w;      w += (size_t)E * 8;
    unsigned* xh      = (unsigned*)w;  w += (size_t)N * 44 * 2;   // x in bf16
    float*    aggX    = (float*)w;     w += (size_t)N * 44 * 4;   // agg1 out (fp32)
    float*    buf1    = (float*)w;     w += (size_t)N * 128 * 4;  // h1 (fp32)
    unsigned* bufAh   = (unsigned*)w;  w += (size_t)N * 64 * 2;   // t2 (bf16)
    float*    aggA    = (float*)w;     w += (size_t)N * 64 * 4;   // agg2 out (fp32)
    unsigned* bufBh   = (unsigned*)w;  w += (size_t)N * 32 * 2;   // t3 (bf16)
    float*    aggB    = (float*)w;                                 // agg3 out (fp32)

    const int B   = 256;
    const int NB  = (N + B - 1) / B;        // 196
    const int NBX = 200;                    // multiple of 8 (XCD count)

    // ---- CSR build + x packing ----
    k_zero     <<<NB, B, 0, stream>>>(degc, N);
    k_packx    <<<(N * 22 + B - 1) / B, B, 0, stream>>>(x, xh, N * 22);
    k_count    <<<(E + B - 1) / B, B, 0, stream>>>(dst, degc, E);
    k_blocksum <<<NB, B, 0, stream>>>(degc, bsum, N);
    k_scanbsum <<<1, B, 0, stream>>>(bsum, NB);
    k_rowptr   <<<NB, B, 0, stream>>>(degc, bsum, row_ptr, cursor, dinv, N);
    k_fill     <<<(E + B - 1) / B, B, 0, stream>>>(src, dst, dinv, cursor, csr_ew, E);

    // ---- layer 1: agg x(bf16,44) -> gemm 44->128 (+b1, relu) ----
    k_agg<11, false><<<(N * 11 + B - 1) / B, B, 0, stream>>>(
        xh, dinv, row_ptr, csr_ew, nullptr, aggX, N);
    k_gemm<44, 128, 16, true, false><<<dim3(NBX, 8), B, 0, stream>>>(aggX, W1, b1, buf1, N);

    // ---- layer 2: gemm 128->64 (bf16 out), agg (+b2, relu) ----
    k_gemm<128, 64, 16, false, true><<<dim3(NBX, 4), B, 0, stream>>>(buf1, W2, nullptr, bufAh, N);
    k_agg<16, true><<<(N * 16 + B - 1) / B, B, 0, stream>>>(
        bufAh, dinv, row_ptr, csr_ew, b2, aggA, N);

    // ---- layer 3: gemm 64->32 (bf16 out), agg (+b3, relu) ----
    k_gemm<64, 32, 8, false, true><<<dim3(NBX, 4), B, 0, stream>>>(aggA, W3, nullptr, bufBh, N);
    k_agg<8, true><<<(N * 8 + B - 1) / B, B, 0, stream>>>(
        bufBh, dinv, row_ptr, csr_ew, b3, aggB, N);

    // ---- MLP head ----
    k_mlp<<<(N + 63) / 64, 64, 0, stream>>>(aggB, Wf1, bf1, Wf2, bf2, out, N);
}